// Round 12
// baseline (155.721 us; speedup 1.0000x reference)
//
#include <hip/hip_runtime.h>
#include <hip/hip_bf16.h>
#include <math.h>

#define NB   2
#define DIM  256
#define NH   4
#define DH   64
#define LEN  4096
#define EPSBN 1e-5f
#define QSC  0.18033688f   // 0.125 * log2(e): softmax in exp2 domain

typedef __attribute__((ext_vector_type(8))) short bf16x8;
typedef __attribute__((ext_vector_type(4))) float f32x4;
typedef __attribute__((ext_vector_type(16))) float f32x16;
typedef __attribute__((ext_vector_type(4))) unsigned short u16x4;
typedef unsigned short ushortT;

__device__ __forceinline__ unsigned short f2bf(float f) {
    unsigned int u = __float_as_uint(f);
    u += 0x7FFFu + ((u >> 16) & 1u);
    return (unsigned short)(u >> 16);
}
__device__ __forceinline__ float bf2f(unsigned short u) {
    return __uint_as_float(((unsigned int)u) << 16);
}
__device__ __forceinline__ unsigned int cvtpk_bf16(float lo, float hi) {
    unsigned int r;
    asm volatile("v_cvt_pk_bf16_f32 %0, %1, %2" : "=v"(r) : "v"(lo), "v"(hi));
    return r;
}
__device__ __forceinline__ float sum16(const f32x16& v) {
    float s01 = v[0] + v[1], s23 = v[2] + v[3], s45 = v[4] + v[5], s67 = v[6] + v[7];
    float s89 = v[8] + v[9], sab = v[10] + v[11], scd = v[12] + v[13], sef = v[14] + v[15];
    return ((s01 + s23) + (s45 + s67)) + ((s89 + sab) + (scd + sef));
}
#define MFMA(a, b, c)   __builtin_amdgcn_mfma_f32_16x16x32_bf16((a), (b), (c), 0, 0, 0)
#define MFMA32(a, b, c) __builtin_amdgcn_mfma_f32_32x32x16_bf16((a), (b), (c), 0, 0, 0)

// ---------------------------------------------------------------------------
// Fused prep (unchanged): weight transposes, W1 x-half, W2T, biases,
// activation packT, Wo*W1m weight-fusion (y=8).
// ---------------------------------------------------------------------------
__global__ __launch_bounds__(256)
void prep_all(const float* __restrict__ x, const float* __restrict__ src,
              const float* __restrict__ Wq, const float* __restrict__ Wk,
              const float* __restrict__ Wv, const float* __restrict__ Wo,
              const float* __restrict__ W1, const float* __restrict__ W2,
              const float* __restrict__ bq, const float* __restrict__ bk,
              const float* __restrict__ bv, const float* __restrict__ bo,
              const float* __restrict__ b1v,
              ushortT* WqT, ushortT* WkT, ushortT* WvT,
              ushortT* W1fT, ushortT* W2T,
              float* bqs, float* bks, float* bvs, float* bfused,
              ushortT* __restrict__ xT, ushortT* __restrict__ srcT)
{
    const int y = blockIdx.y;
    const int idx = blockIdx.x * 256 + threadIdx.x;
    const int t = threadIdx.x;
    if (y <= 2) {
        if (idx < 65536) {
            int op = idx >> 8, i = idx & 255;
            int o = (op & 63) * 4 + (op >> 6);
            if (y == 0)      WqT[idx] = f2bf(Wq[i * 256 + o] * QSC);
            else if (y == 1) WkT[idx] = f2bf(Wk[i * 256 + o]);
            else             WvT[idx] = f2bf(Wv[i * 256 + o]);
        }
    } else if (y == 3) {
        int o = idx >> 9, i = idx & 511;
        if (i < 256) W1fT[o * 512 + i] = f2bf(W1[i * 512 + o]);
    } else if (y == 4) {
        if (idx < 131072) { int o = idx >> 9, i = idx & 511; W2T[idx] = f2bf(W2[i * 256 + o]); }
    } else if (y == 5) {
        if (blockIdx.x == 0 && idx < 256) {
            int o = (idx & 63) * 4 + (idx >> 6);
            bqs[idx] = bq[o] * QSC;
            bks[idx] = bk[o];
            bvs[idx] = bv[o];
        }
    } else if (y <= 7) {
        const int bid = blockIdx.x + (y - 6) * 1024;
        const int c0 = (bid & 31) * 8;
        const int n0 = ((bid >> 5) & 15) * 256;
        const int z = bid >> 9;
        const int b = z & 1;
        const float* in = (z >> 1) ? src : x;
        ushortT* out = (z >> 1) ? srcT : xT;
        const int n = n0 + t;
        bf16x8 v;
#pragma unroll
        for (int j = 0; j < 8; ++j)
            v[j] = (short)f2bf(in[(((b << 8) + c0 + j) << 12) + n]);
        *(bf16x8*)&out[(((b << 12) + n) << 8) + c0] = v;
    } else {
        if (blockIdx.x >= 40) return;
        const int oy = blockIdx.x / 5, xi = blockIdx.x % 5;
        __shared__ float red[4][64];
        if (xi == 4) {
            const int part = t >> 6, oo = t & 63;
            const int o = oy * 64 + oo;
            float s = 0.f;
            for (int c = part * 64; c < part * 64 + 64; ++c)
                s += bo[c] * W1[(256 + c) * 512 + o];
            red[part][oo] = s;
            __syncthreads();
            if (part == 0)
                bfused[o] = ((red[0][oo] + red[1][oo]) + (red[2][oo] + red[3][oo])) + b1v[o];
            return;
        }
        const int w = t >> 6, l2 = t & 63, lg = l2 >> 4, ll = l2 & 15;
        const int wr = w >> 1, wc = w & 1;
        const int a0t = xi * 64, o0 = oy * 64;
        const int oA = o0 + wr * 32;
        const int aB = a0t + wc * 32;
        f32x4 acc[2][2] = {};
        const int ra = aB + ll, rb = aB + 16 + ll;
        const int r0 = (ra & 63) * 4 + (ra >> 6);
        const int r1 = (rb & 63) * 4 + (rb >> 6);
#pragma unroll
        for (int kk = 0; kk < 256; kk += 32) {
            const int cbase = 256 + kk + lg * 8;
            bf16x8 a0, a1;
#pragma unroll
            for (int j = 0; j < 8; ++j) {
                a0[j] = (short)f2bf(W1[(size_t)(cbase + j) * 512 + oA + ll]);
                a1[j] = (short)f2bf(W1[(size_t)(cbase + j) * 512 + oA + 16 + ll]);
            }
            const float* p0 = Wo + r0 * 256 + kk + lg * 8;
            const float* p1 = Wo + r1 * 256 + kk + lg * 8;
            float4 f00 = *(const float4*)p0, f01 = *(const float4*)(p0 + 4);
            float4 f10 = *(const float4*)p1, f11 = *(const float4*)(p1 + 4);
            bf16x8 b0, b1;
            b0[0] = (short)f2bf(f00.x); b0[1] = (short)f2bf(f00.y);
            b0[2] = (short)f2bf(f00.z); b0[3] = (short)f2bf(f00.w);
            b0[4] = (short)f2bf(f01.x); b0[5] = (short)f2bf(f01.y);
            b0[6] = (short)f2bf(f01.z); b0[7] = (short)f2bf(f01.w);
            b1[0] = (short)f2bf(f10.x); b1[1] = (short)f2bf(f10.y);
            b1[2] = (short)f2bf(f10.z); b1[3] = (short)f2bf(f10.w);
            b1[4] = (short)f2bf(f11.x); b1[5] = (short)f2bf(f11.y);
            b1[6] = (short)f2bf(f11.z); b1[7] = (short)f2bf(f11.w);
            acc[0][0] = MFMA(a0, b0, acc[0][0]);
            acc[0][1] = MFMA(a0, b1, acc[0][1]);
            acc[1][0] = MFMA(a1, b0, acc[1][0]);
            acc[1][1] = MFMA(a1, b1, acc[1][1]);
        }
#pragma unroll
        for (int f = 0; f < 2; ++f)
#pragma unroll
            for (int g = 0; g < 2; ++g) {
                const int ap = aB + g * 16 + ll;
#pragma unroll
                for (int r = 0; r < 4; ++r) {
                    const int o = oA + f * 16 + lg * 4 + r;
                    W1fT[o * 512 + 256 + ap] = f2bf(acc[f][g][r]);
                }
            }
    }
}

// ===========================================================================
// LDS-staged 128x128-tile GEMM core (unchanged from round 11).
// ===========================================================================
#define GEMM_STAGE(AROWP, BROWP)                                              \
    {                                                                         \
        _Pragma("unroll")                                                     \
        for (int i_ = 0; i_ < 4; ++i_) {                                      \
            const int row_ = i_ * 32 + srow;                                  \
            bf16x8 va_ = *(const bf16x8*)(AROWP(row_) + sc8 * 8);             \
            bf16x8 vb_ = *(const bf16x8*)(BROWP(row_) + sc8 * 8);             \
            const int dst_ = (row_ * 8 + (sc8 ^ (row_ & 7))) * 8;             \
            *(bf16x8*)&ldsA[dst_] = va_;                                      \
            *(bf16x8*)&ldsB[dst_] = vb_;                                      \
        }                                                                     \
    }

#define GEMM_FRAGS(k2_)                                                       \
    bf16x8 af[4], bfr[4];                                                     \
    {                                                                         \
        _Pragma("unroll")                                                     \
        for (int fo_ = 0; fo_ < 4; ++fo_) {                                   \
            const int ra_ = wr * 64 + fo_ * 16 + ll;                          \
            af[fo_] = *(const bf16x8*)&ldsA[(ra_ * 8 + (((k2_) * 4 + lg) ^ (ra_ & 7))) * 8]; \
            const int rb_ = wc * 64 + fo_ * 16 + ll;                          \
            bfr[fo_] = *(const bf16x8*)&ldsB[(rb_ * 8 + (((k2_) * 4 + lg) ^ (rb_ & 7))) * 8]; \
        }                                                                     \
    }

#define GEMM_MFMA16()                                                         \
    _Pragma("unroll")                                                         \
    for (int fo_ = 0; fo_ < 4; ++fo_) {                                       \
        _Pragma("unroll")                                                     \
        for (int fn_ = 0; fn_ < 4; ++fn_)                                     \
            acc[fo_][fn_] = MFMA(af[fo_], bfr[fn_], acc[fo_][fn_]);           \
    }

// ---------------------------------------------------------------------------
// QKV projections, LDS-staged (unchanged).
// ---------------------------------------------------------------------------
__global__ __launch_bounds__(256)
void qkv128(const ushortT* __restrict__ xT, const ushortT* __restrict__ srcT,
            const ushortT* __restrict__ WqT, const ushortT* __restrict__ WkT,
            const ushortT* __restrict__ WvT,
            const float* __restrict__ bqs, const float* __restrict__ bks,
            const float* __restrict__ bvs,
            ushortT* __restrict__ QT, ushortT* __restrict__ KT,
            ushortT* __restrict__ Vb)
{
    __shared__ __align__(16) ushortT ldsA[8192];
    __shared__ __align__(16) ushortT ldsB[8192];
    const int z = blockIdx.z, sel = z >> 1, b = z & 1;
    const int t = threadIdx.x, w = t >> 6, l = t & 63, lg = l >> 4, ll = l & 15;
    const int wr = w >> 1, wc = w & 1;
    const int n0 = blockIdx.x * 128, o0 = blockIdx.y * 128;
    const int srow = t >> 3, sc8 = t & 7;

    const ushortT* Agl;
    const ushortT* Bgl;
    int Arb, Brb;
    if (sel == 0)      { Agl = WqT;  Arb = o0;              Bgl = xT;   Brb = (b << 12) + n0; }
    else if (sel == 1) { Agl = WkT;  Arb = o0;              Bgl = srcT; Brb = (b << 12) + n0; }
    else               { Agl = srcT; Arb = (b << 12) + n0;  Bgl = WvT;  Brb = o0; }

    f32x4 acc[4][4] = {};
#define AROW(r_) (Agl + (size_t)(Arb + (r_)) * 256 + kk)
#define BROW(r_) (Bgl + (size_t)(Brb + (r_)) * 256 + kk)
    for (int kk = 0; kk < 256; kk += 64) {
        GEMM_STAGE(AROW, BROW);
        __syncthreads();
#pragma unroll
        for (int k2 = 0; k2 < 2; ++k2) {
            GEMM_FRAGS(k2);
            GEMM_MFMA16();
        }
        __syncthreads();
    }
#undef AROW
#undef BROW

    if (sel < 2) {
        const float* bias = sel ? bks : bqs;
        ushortT* out = sel ? KT : QT;
#pragma unroll
        for (int f = 0; f < 4; ++f) {
            const int ob = o0 + wr * 64 + f * 16 + lg * 4;
            f32x4 bv = *(const f32x4*)&bias[ob];
            const int hh = ob >> 6, d = ob & 63;
#pragma unroll
            for (int g = 0; g < 4; ++g) {
                const int n = n0 + wc * 64 + g * 16 + ll;
                u16x4 pk;
#pragma unroll
                for (int r = 0; r < 4; ++r) pk[r] = f2bf(acc[f][g][r] + bv[r]);
                *(u16x4*)&out[((((b << 2) + hh) << 12) + n) * 64 + d] = pk;
            }
        }
    } else {
#pragma unroll
        for (int g = 0; g < 4; ++g) {
            const int op = o0 + wc * 64 + g * 16 + ll;
            const float bb = bvs[op];
            const int hh = op >> 6, d = op & 63;
#pragma unroll
            for (int f = 0; f < 4; ++f) {
                const int m = n0 + wr * 64 + f * 16 + lg * 4;
                u16x4 pk;
#pragma unroll
                for (int r = 0; r < 4; ++r) pk[r] = f2bf(acc[f][g][r] + bb);
                *(u16x4*)&Vb[((((b << 2) + hh) << 6) + d) * 4096 + m] = pk;
            }
        }
    }
}

// ---------------------------------------------------------------------------
// h-GEMM (unchanged).
// ---------------------------------------------------------------------------
__global__ __launch_bounds__(256)
void gemmh128(const ushortT* __restrict__ xT, const ushortT* __restrict__ attnT,
              const ushortT* __restrict__ W1fT, const float* __restrict__ bfused,
              ushortT* __restrict__ hT, float* __restrict__ Sp, float* __restrict__ SSp)
{
    __shared__ __align__(16) ushortT ldsA[8192];
    __shared__ __align__(16) ushortT ldsB[8192];
    const int t = threadIdx.x, w = t >> 6, l = t & 63, lg = l >> 4, ll = l & 15;
    const int wr = w >> 1, wc = w & 1;
    const int n0 = blockIdx.x * 128, o0 = blockIdx.y * 128, b = blockIdx.z;
    const int srow = t >> 3, sc8 = t & 7;

    f32x4 acc[4][4] = {};
    for (int kk = 0; kk < 512; kk += 64) {
        const ushortT* Bsrc = (kk < 256) ? xT : attnT;
        const int kb = kk & 255;
#define AROW(r_) (W1fT + (size_t)(o0 + (r_)) * 512 + kk)
#define BROW(r_) (Bsrc + (size_t)((b << 12) + n0 + (r_)) * 256 + kb)
        GEMM_STAGE(AROW, BROW);
#undef AROW
#undef BROW
        __syncthreads();
#pragma unroll
        for (int k2 = 0; k2 < 2; ++k2) {
            GEMM_FRAGS(k2);
            GEMM_MFMA16();
        }
        __syncthreads();
    }

#pragma unroll
    for (int f = 0; f < 4; ++f) {
        const int ob = o0 + wr * 64 + f * 16 + lg * 4;
        f32x4 bv = *(const f32x4*)&bfused[ob];
        f32x4 hv[4];
#pragma unroll
        for (int g = 0; g < 4; ++g) {
            const int n = n0 + wc * 64 + g * 16 + ll;
            u16x4 pk;
#pragma unroll
            for (int r = 0; r < 4; ++r) {
                hv[g][r] = acc[f][g][r] + bv[r];
                pk[r] = f2bf(hv[g][r]);
            }
            *(u16x4*)&hT[(((b << 12) + n) << 9) + ob] = pk;
        }
#pragma unroll
        for (int r = 0; r < 4; ++r) {
            float s  = (hv[0][r] + hv[1][r]) + (hv[2][r] + hv[3][r]);
            float q2 = (hv[0][r] * hv[0][r] + hv[1][r] * hv[1][r]) +
                       (hv[2][r] * hv[2][r] + hv[3][r] * hv[3][r]);
#pragma unroll
            for (int off = 1; off < 16; off <<= 1) {
                s  += __shfl_xor(s, off);
                q2 += __shfl_xor(q2, off);
            }
            if (ll == 0) {
                const int o = ob + r;
                const int pidx = (o * 2 + b) * 64 + blockIdx.x * 2 + wc;
                Sp[pidx] = s;
                SSp[pidx] = q2;
            }
        }
    }
}

// ---------------------------------------------------------------------------
// BN finalize (unchanged).
// ---------------------------------------------------------------------------
__global__ __launch_bounds__(128)
void bn_fin2(const float* __restrict__ S, const float* __restrict__ SS,
             const float* __restrict__ gamma, const float* __restrict__ beta,
             float* __restrict__ scale, float* __restrict__ shift)
{
    const int c = blockIdx.x, t = threadIdx.x;
    float s = S[c * 128 + t];
    float ss = SS[c * 128 + t];
#pragma unroll
    for (int off = 32; off; off >>= 1) {
        s += __shfl_down(s, off);
        ss += __shfl_down(ss, off);
    }
    __shared__ float red[4];
    const int wid = t >> 6;
    if ((t & 63) == 0) { red[wid] = s; red[2 + wid] = ss; }
    __syncthreads();
    if (t == 0) {
        s = red[0] + red[1];
        ss = red[2] + red[3];
        const float cnt = (float)NB * (float)LEN;
        float mean = s / cnt;
        float var = ss / cnt - mean * mean;
        float sc = gamma[c] * rsqrtf(var + EPSBN);
        scale[c] = sc;
        shift[c] = beta[c] - mean * sc;
    }
}

// ---------------------------------------------------------------------------
// Final GEMM (unchanged).
// ---------------------------------------------------------------------------
__global__ __launch_bounds__(256)
void gemmw2_128(const ushortT* __restrict__ hT, const ushortT* __restrict__ W2T,
                const float* __restrict__ bias, const float* __restrict__ scale,
                const float* __restrict__ shift, float* __restrict__ out)
{
    __shared__ __align__(16) ushortT ldsA[8192];
    __shared__ __align__(16) ushortT ldsB[8192];
    const int t = threadIdx.x, w = t >> 6, l = t & 63, lg = l >> 4, ll = l & 15;
    const int wr = w >> 1, wc = w & 1;
    const int n0 = blockIdx.x * 128, o0 = blockIdx.y * 128, b = blockIdx.z;
    const int srow = t >> 3, sc8 = t & 7;

    f32x4 acc[4][4] = {};
    for (int kk = 0; kk < 512; kk += 64) {
#define AROW(r_) (W2T + (size_t)(o0 + (r_)) * 512 + kk)
#define BROW(r_) (hT + (size_t)((b << 12) + n0 + (r_)) * 512 + kk)
        GEMM_STAGE(AROW, BROW);
#undef AROW
#undef BROW
        __syncthreads();
#pragma unroll
        for (int k2 = 0; k2 < 2; ++k2) {
            GEMM_FRAGS(k2);
            const int ch = kk + k2 * 32 + lg * 8;
            f32x4 sc0 = *(const f32x4*)&scale[ch];
            f32x4 sc1 = *(const f32x4*)&scale[ch + 4];
            f32x4 sh0 = *(const f32x4*)&shift[ch];
            f32x4 sh1 = *(const f32x4*)&shift[ch + 4];
#pragma unroll
            for (int fn = 0; fn < 4; ++fn) {
                bf16x8 raw = bfr[fn], bb;
#pragma unroll
                for (int j = 0; j < 4; ++j) {
                    float v0 = fmaxf(bf2f((unsigned short)raw[j]) * sc0[j] + sh0[j], 0.f);
                    float v1 = fmaxf(bf2f((unsigned short)raw[j + 4]) * sc1[j] + sh1[j], 0.f);
                    bb[j] = (short)f2bf(v0);
                    bb[j + 4] = (short)f2bf(v1);
                }
                bfr[fn] = bb;
            }
            GEMM_MFMA16();
        }
        __syncthreads();
    }

#pragma unroll
    for (int f = 0; f < 4; ++f) {
        const int ob = o0 + wr * 64 + f * 16 + lg * 4;
        f32x4 bv = *(const f32x4*)&bias[ob];
#pragma unroll
        for (int g = 0; g < 4; ++g) {
            const int n = n0 + wc * 64 + g * 16 + ll;
#pragma unroll
            for (int r = 0; r < 4; ++r)
                out[(((b << 8) + ob + r) << 12) + n] = acc[f][g][r] + bv[r];
        }
    }
}

// ---------------------------------------------------------------------------
// Flash attention v11: attn9 + T15 software pipeline. Two score buffers:
// QK(s+1) runs on the MFMA pipe while softmax(s) runs on the VALU pipe.
// Static A/B naming (no runtime-indexed buffers). 64q/wave, 4-wave key
// split, grid 512, native v_exp, phased LDS merge.
// ---------------------------------------------------------------------------
struct KF { bf16x8 a, b, c, d; };

__device__ __forceinline__ KF loadK(const ushortT* p) {
    KF k;
    k.a = *(const bf16x8*)(p);
    k.b = *(const bf16x8*)(p + 16);
    k.c = *(const bf16x8*)(p + 32);
    k.d = *(const bf16x8*)(p + 48);
    return k;
}
__device__ __forceinline__ KF loadV(const ushortT* p) {
    KF v;
    v.a = *(const bf16x8*)(p);
    v.b = *(const bf16x8*)(p + 16);
    v.c = *(const bf16x8*)(p + 32 * 4096);
    v.d = *(const bf16x8*)(p + 32 * 4096 + 16);
    return v;
}
__device__ __forceinline__ void qk8(const KF& k, const bf16x8 qf[2][4],
                                    f32x16& s0, f32x16& s1) {
    f32x16 z0 = {}, z1 = {};
    __builtin_amdgcn_s_setprio(1);
    z0 = MFMA32(k.a, qf[0][0], z0); z1 = MFMA32(k.a, qf[1][0], z1);
    z0 = MFMA32(k.b, qf[0][1], z0); z1 = MFMA32(k.b, qf[1][1], z1);
    z0 = MFMA32(k.c, qf[0][2], z0); z1 = MFMA32(k.c, qf[1][2], z1);
    z0 = MFMA32(k.d, qf[0][3], z0); z1 = MFMA32(k.d, qf[1][3], z1);
    __builtin_amdgcn_s_setprio(0);
    s0 = z0; s1 = z1;
}
__device__ __forceinline__ void smax(f32x16& s0, f32x16& s1,
                                     bf16x8* pb0, bf16x8* pb1, float* l_loc) {
#pragma unroll
    for (int r = 0; r < 16; ++r) s0[r] = __builtin_amdgcn_exp2f(s0[r]);
#pragma unroll
    for (int r = 0; r < 16; ++r) s1[r] = __builtin_amdgcn_exp2f(s1[r]);
    l_loc[0] += sum16(s0);
    l_loc[1] += sum16(s1);
    unsigned int pk0[8], pk1[8];
#pragma unroll
    for (int j = 0; j < 8; ++j) {
        pk0[j] = cvtpk_bf16(s0[2 * j], s0[2 * j + 1]);
        pk1[j] = cvtpk_bf16(s1[2 * j], s1[2 * j + 1]);
    }
#pragma unroll
    for (int sb = 0; sb < 2; ++sb) {
        unsigned int a0 = pk0[4 * sb], b0 = pk0[4 * sb + 2];
        unsigned int a1 = pk0[4 * sb + 1], b1 = pk0[4 * sb + 3];
        asm volatile("v_permlane32_swap_b32 %0, %1" : "+v"(a0), "+v"(b0));
        asm volatile("v_permlane32_swap_b32 %0, %1" : "+v"(a1), "+v"(b1));
        union { unsigned int u[4]; bf16x8 v; } tp;
        tp.u[0] = a0; tp.u[1] = a1; tp.u[2] = b0; tp.u[3] = b1;
        pb0[sb] = tp.v;
        unsigned int c0 = pk1[4 * sb], d0 = pk1[4 * sb + 2];
        unsigned int c1 = pk1[4 * sb + 1], d1 = pk1[4 * sb + 3];
        asm volatile("v_permlane32_swap_b32 %0, %1" : "+v"(c0), "+v"(d0));
        asm volatile("v_permlane32_swap_b32 %0, %1" : "+v"(c1), "+v"(d1));
        union { unsigned int u[4]; bf16x8 v; } tq;
        tq.u[0] = c0; tq.u[1] = c1; tq.u[2] = d0; tq.u[3] = d1;
        pb1[sb] = tq.v;
    }
}
__device__ __forceinline__ void pv8(const KF& v, const bf16x8* pb0,
                                    const bf16x8* pb1, f32x16 o[2][2]) {
    __builtin_amdgcn_s_setprio(1);
    o[0][0] = MFMA32(v.a, pb0[0], o[0][0]);
    o[1][0] = MFMA32(v.a, pb1[0], o[1][0]);
    o[0][0] = MFMA32(v.b, pb0[1], o[0][0]);
    o[1][0] = MFMA32(v.b, pb1[1], o[1][0]);
    o[0][1] = MFMA32(v.c, pb0[0], o[0][1]);
    o[1][1] = MFMA32(v.c, pb1[0], o[1][1]);
    o[0][1] = MFMA32(v.d, pb0[1], o[0][1]);
    o[1][1] = MFMA32(v.d, pb1[1], o[1][1]);
    __builtin_amdgcn_s_setprio(0);
}

__global__ __launch_bounds__(256)
void attn11(const ushortT* __restrict__ QT, const ushortT* __restrict__ KT,
            const ushortT* __restrict__ Vg, ushortT* __restrict__ attnT)
{
    __shared__ __align__(16) float olds[6144];
    __shared__ float llds[192];
    const int t = threadIdx.x, w = t >> 6, l = t & 63;
    const int hi = l >> 5, ln = l & 31;
    const int f = blockIdx.x, bh = f & 7, nt = f >> 3;
    const int b = bh >> 2, h = bh & 3;
    const int n0 = nt * 64;

    bf16x8 qf[2][4];
#pragma unroll
    for (int qb = 0; qb < 2; ++qb) {
        const int qrow = ((bh << 12) + n0 + qb * 32 + ln) * 64 + hi * 8;
#pragma unroll
        for (int dblk = 0; dblk < 4; ++dblk)
            qf[qb][dblk] = *(const bf16x8*)&QT[qrow + dblk * 16];
    }

    f32x16 o[2][2] = {};
    float l_loc[2] = {0.f, 0.f};

    const ushortT* Kb0 = KT + ((bh << 12) + w * 32 + ln) * 64 + hi * 8;
    const ushortT* Vb0 = Vg + ((bh << 6) + ln) * 4096 + w * 32 + hi * 8;
#define KSTEP (128 * 64)

    // prologue: scores(0) into stA; K(1) in flight as kB
    KF kt = loadK(Kb0);
    KF kB = loadK(Kb0 + KSTEP);
    f32x16 stA0, stA1;
    qk8(kt, qf, stA0, stA1);

#pragma unroll 1
    for (int s = 0; s < 32; s += 2) {
        // --- phase A: consume scores(s)=stA, K(s+1)=kB; produce scores(s+1) ---
        {
            const int sk = (s + 2 < 32) ? s + 2 : 31;
            KF kC = loadK(Kb0 + sk * KSTEP);          // in flight for phase B
            KF vA = loadV(Vb0 + s * 128);             // in flight, used below
            f32x16 stB0, stB1;
            qk8(kB, qf, stB0, stB1);                  // MFMA pipe
            bf16x8 pA0[2], pA1[2];
            smax(stA0, stA1, pA0, pA1, l_loc);        // VALU pipe (overlaps)
            pv8(vA, pA0, pA1, o);
            // --- phase B: consume scores(s+1)=stB, K(s+2)=kC ---
            const int sk2 = (s + 3 < 32) ? s + 3 : 31;
            kB = loadK(Kb0 + sk2 * KSTEP);            // in flight for next A
            KF vB = loadV(Vb0 + (s + 1) * 128);
            qk8(kC, qf, stA0, stA1);                  // scores(s+2) -> stA
            bf16x8 pB0[2], pB1[2];
            smax(stB0, stB1, pB0, pB1, l_loc);
            pv8(vB, pB0, pB1, o);
        }
    }
#undef KSTEP

    // ---- merge 4 key-split waves (phased per qb, 24KB LDS) ----
    float lw[2];
    lw[0] = l_loc[0] + __shfl_xor(l_loc[0], 32);
    lw[1] = l_loc[1] + __shfl_xor(l_loc[1], 32);
    if (w && hi == 0) {
        llds[(w - 1) * 64 + ln] = lw[0];
        llds[(w - 1) * 64 + 32 + ln] = lw[1];
    }
#pragma unroll
    for (int qb = 0; qb < 2; ++qb) {
        if (w) {
            const int base = (w - 1) * 2048 + l;
#pragma unroll
            for (int r = 0; r < 16; ++r) olds[base + r * 64] = o[qb][0][r];
#pragma unroll
            for (int r = 0; r < 16; ++r) olds[base + (16 + r) * 64] = o[qb][1][r];
        }
        __syncthreads();
        if (w == 0) {
#pragma unroll
            for (int j = 0; j < 3; ++j) {
                const int base = j * 2048 + l;
#pragma unroll
                for (int r = 0; r < 16; ++r) o[qb][0][r] += olds[base + r * 64];
#pragma unroll
                for (int r = 0; r < 16; ++r) o[qb][1][r] += olds[base + (16 + r) * 64];
            }
        }
        __syncthreads();
    }

    if (w == 0) {
        float li[2] = {lw[0], lw[1]};
#pragma unroll
        for (int j = 0; j < 3; ++j) {
            li[0] += llds[j * 64 + ln];
            li[1] += llds[j * 64 + 32 + ln];
        }
#pragma unroll
        for (int qb = 0; qb < 2; ++qb) {
            const float linv = 1.f / li[qb];
            ushortT* orow = attnT + ((((b << 12) + n0 + qb * 32 + ln)) << 8) + (h << 6);
#pragma unroll
            for (int j = 0; j < 8; ++j) {
                const int d0 = ((2 * j) & 3) + 8 * (j >> 1) + 4 * hi;
                *(unsigned int*)&orow[d0] =
                    cvtpk_bf16(o[qb][0][2 * j] * linv, o[qb][0][2 * j + 1] * linv);
                *(unsigned int*)&orow[32 + d0] =
                    cvtpk_bf16(o[qb][1][2 * j] * linv, o[qb][1][2 * j + 1] * linv);
            }
        }
    }
}

extern "C" void kernel_launch(void* const* d_in, const int* in_sizes, int n_in,
                              void* d_out, int out_size, void* d_ws, size_t ws_size,
                              hipStream_t stream)
{
    const float* x   = (const float*)d_in[0];
    const float* src = (const float*)d_in[1];
    const float* Wq  = (const float*)d_in[2];
    const float* bq  = (const float*)d_in[3];
    const float* Wk  = (const float*)d_in[4];
    const float* bk  = (const float*)d_in[5];
    const float* Wv  = (const float*)d_in[6];
    const float* bv  = (const float*)d_in[7];
    const float* Wo  = (const float*)d_in[8];
    const float* bo  = (const float*)d_in[9];
    const float* W1  = (const float*)d_in[10];
    const float* b1  = (const float*)d_in[11];
    const float* gam = (const float*)d_in[12];
    const float* bet = (const float*)d_in[13];
    const float* W2  = (const float*)d_in[14];
    const float* b2  = (const float*)d_in[15];
    float* outp = (float*)d_out;

    char* W = (char*)d_ws;
    ushortT* xT    = (ushortT*)(W);                       // 4MB [2][4096][256]
    ushortT* srcT  = (ushortT*)(W + (4u << 20));          // 4MB
    ushortT* QT    = (ushortT*)(W + (8u << 20));          // 4MB [b][h][n][d]
    ushortT* KT    = (ushortT*)(W + (12u << 20));         // 4MB [b][h][m][d]
    ushortT* Vb    = (ushortT*)(W + (16u << 20));         // 4MB [b][h][d][m]
    ushortT* attnT = (ushortT*)(W + (20u << 20));         // 4MB [b][n][256]
    ushortT* hT    = KT;                                  // 8MB overlays KT+Vb (dead)
    float* Sp  = (float*)(W + (8u << 20));                // 256KB overlays QT (dead)
    float* SSp = (float*)(W + (9u << 20));                // 256KB
    char* WB = W + (24u << 20);
    ushortT* WqT  = (ushortT*)(WB);                       // 128KB
    ushortT* WkT  = (ushortT*)(WB + (128u << 10));
    ushortT* WvT  = (ushortT*)(WB + (256u << 10));
    ushortT* W1fT = (ushortT*)(WB + (640u << 10));        // 512KB [512][512]
    ushortT* W2T  = (ushortT*)(WB + (1152u << 10));       // 256KB [256][512]
    float* bqs    = (float*)(WB + (1408u << 10));
    float* bks    = (float*)(WB + (1409u << 10));
    float* bvs    = (float*)(WB + (1410u << 10));
    float* bfused = (float*)(WB + (1412u << 10));         // 2KB
    float* scl    = (float*)(WB + (1416u << 10));
    float* sft    = (float*)(WB + (1418u << 10));

    prep_all<<<dim3(1024, 9), 256, 0, stream>>>(x, src, Wq, Wk, Wv, Wo, W1, W2,
                                                bq, bk, bv, bo, b1,
                                                WqT, WkT, WvT, W1fT, W2T,
                                                bqs, bks, bvs, bfused, xT, srcT);

    qkv128<<<dim3(32, 2, 6), 256, 0, stream>>>(xT, srcT, WqT, WkT, WvT,
                                               bqs, bks, bvs, QT, KT, Vb);

    attn11<<<dim3(512), dim3(256), 0, stream>>>(QT, KT, Vb, attnT);

    gemmh128<<<dim3(32, 4, 2), 256, 0, stream>>>(xT, attnT, W1fT, bfused, hT, Sp, SSp);

    bn_fin2<<<dim3(512), 128, 0, stream>>>(Sp, SSp, gam, bet, scl, sft);

    gemmw2_128<<<dim3(32, 2, 2), 256, 0, stream>>>(hT, W2T, b2, scl, sft, outp);
}

// Round 13
// 144.742 us; speedup vs baseline: 1.0759x; 1.0759x over previous
//
#include <hip/hip_runtime.h>
#include <hip/hip_bf16.h>
#include <math.h>

#define NB   2
#define DIM  256
#define NH   4
#define DH   64
#define LEN  4096
#define EPSBN 1e-5f
#define QSC  0.18033688f   // 0.125 * log2(e): softmax in exp2 domain

typedef __attribute__((ext_vector_type(8))) short bf16x8;
typedef __attribute__((ext_vector_type(4))) float f32x4;
typedef __attribute__((ext_vector_type(16))) float f32x16;
typedef __attribute__((ext_vector_type(4))) unsigned short u16x4;
typedef unsigned short ushortT;

__device__ __forceinline__ unsigned short f2bf(float f) {
    unsigned int u = __float_as_uint(f);
    u += 0x7FFFu + ((u >> 16) & 1u);
    return (unsigned short)(u >> 16);
}
__device__ __forceinline__ float bf2f(unsigned short u) {
    return __uint_as_float(((unsigned int)u) << 16);
}
__device__ __forceinline__ unsigned int cvtpk_bf16(float lo, float hi) {
    unsigned int r;
    asm volatile("v_cvt_pk_bf16_f32 %0, %1, %2" : "=v"(r) : "v"(lo), "v"(hi));
    return r;
}
__device__ __forceinline__ float sum16(const f32x16& v) {
    float s01 = v[0] + v[1], s23 = v[2] + v[3], s45 = v[4] + v[5], s67 = v[6] + v[7];
    float s89 = v[8] + v[9], sab = v[10] + v[11], scd = v[12] + v[13], sef = v[14] + v[15];
    return ((s01 + s23) + (s45 + s67)) + ((s89 + sab) + (scd + sef));
}
#define MFMA(a, b, c)   __builtin_amdgcn_mfma_f32_16x16x32_bf16((a), (b), (c), 0, 0, 0)
#define MFMA32(a, b, c) __builtin_amdgcn_mfma_f32_32x32x16_bf16((a), (b), (c), 0, 0, 0)

// ---------------------------------------------------------------------------
// Fused prep (unchanged): weight transposes, W1 x-half, W2T, biases,
// activation packT, Wo*W1m weight-fusion (y=8).
// ---------------------------------------------------------------------------
__global__ __launch_bounds__(256)
void prep_all(const float* __restrict__ x, const float* __restrict__ src,
              const float* __restrict__ Wq, const float* __restrict__ Wk,
              const float* __restrict__ Wv, const float* __restrict__ Wo,
              const float* __restrict__ W1, const float* __restrict__ W2,
              const float* __restrict__ bq, const float* __restrict__ bk,
              const float* __restrict__ bv, const float* __restrict__ bo,
              const float* __restrict__ b1v,
              ushortT* WqT, ushortT* WkT, ushortT* WvT,
              ushortT* W1fT, ushortT* W2T,
              float* bqs, float* bks, float* bvs, float* bfused,
              ushortT* __restrict__ xT, ushortT* __restrict__ srcT)
{
    const int y = blockIdx.y;
    const int idx = blockIdx.x * 256 + threadIdx.x;
    const int t = threadIdx.x;
    if (y <= 2) {
        if (idx < 65536) {
            int op = idx >> 8, i = idx & 255;
            int o = (op & 63) * 4 + (op >> 6);
            if (y == 0)      WqT[idx] = f2bf(Wq[i * 256 + o] * QSC);
            else if (y == 1) WkT[idx] = f2bf(Wk[i * 256 + o]);
            else             WvT[idx] = f2bf(Wv[i * 256 + o]);
        }
    } else if (y == 3) {
        int o = idx >> 9, i = idx & 511;
        if (i < 256) W1fT[o * 512 + i] = f2bf(W1[i * 512 + o]);
    } else if (y == 4) {
        if (idx < 131072) { int o = idx >> 9, i = idx & 511; W2T[idx] = f2bf(W2[i * 256 + o]); }
    } else if (y == 5) {
        if (blockIdx.x == 0 && idx < 256) {
            int o = (idx & 63) * 4 + (idx >> 6);
            bqs[idx] = bq[o] * QSC;
            bks[idx] = bk[o];
            bvs[idx] = bv[o];
        }
    } else if (y <= 7) {
        const int bid = blockIdx.x + (y - 6) * 1024;
        const int c0 = (bid & 31) * 8;
        const int n0 = ((bid >> 5) & 15) * 256;
        const int z = bid >> 9;
        const int b = z & 1;
        const float* in = (z >> 1) ? src : x;
        ushortT* out = (z >> 1) ? srcT : xT;
        const int n = n0 + t;
        bf16x8 v;
#pragma unroll
        for (int j = 0; j < 8; ++j)
            v[j] = (short)f2bf(in[(((b << 8) + c0 + j) << 12) + n]);
        *(bf16x8*)&out[(((b << 12) + n) << 8) + c0] = v;
    } else {
        if (blockIdx.x >= 40) return;
        const int oy = blockIdx.x / 5, xi = blockIdx.x % 5;
        __shared__ float red[4][64];
        if (xi == 4) {
            const int part = t >> 6, oo = t & 63;
            const int o = oy * 64 + oo;
            float s = 0.f;
            for (int c = part * 64; c < part * 64 + 64; ++c)
                s += bo[c] * W1[(256 + c) * 512 + o];
            red[part][oo] = s;
            __syncthreads();
            if (part == 0)
                bfused[o] = ((red[0][oo] + red[1][oo]) + (red[2][oo] + red[3][oo])) + b1v[o];
            return;
        }
        const int w = t >> 6, l2 = t & 63, lg = l2 >> 4, ll = l2 & 15;
        const int wr = w >> 1, wc = w & 1;
        const int a0t = xi * 64, o0 = oy * 64;
        const int oA = o0 + wr * 32;
        const int aB = a0t + wc * 32;
        f32x4 acc[2][2] = {};
        const int ra = aB + ll, rb = aB + 16 + ll;
        const int r0 = (ra & 63) * 4 + (ra >> 6);
        const int r1 = (rb & 63) * 4 + (rb >> 6);
#pragma unroll
        for (int kk = 0; kk < 256; kk += 32) {
            const int cbase = 256 + kk + lg * 8;
            bf16x8 a0, a1;
#pragma unroll
            for (int j = 0; j < 8; ++j) {
                a0[j] = (short)f2bf(W1[(size_t)(cbase + j) * 512 + oA + ll]);
                a1[j] = (short)f2bf(W1[(size_t)(cbase + j) * 512 + oA + 16 + ll]);
            }
            const float* p0 = Wo + r0 * 256 + kk + lg * 8;
            const float* p1 = Wo + r1 * 256 + kk + lg * 8;
            float4 f00 = *(const float4*)p0, f01 = *(const float4*)(p0 + 4);
            float4 f10 = *(const float4*)p1, f11 = *(const float4*)(p1 + 4);
            bf16x8 b0, b1;
            b0[0] = (short)f2bf(f00.x); b0[1] = (short)f2bf(f00.y);
            b0[2] = (short)f2bf(f00.z); b0[3] = (short)f2bf(f00.w);
            b0[4] = (short)f2bf(f01.x); b0[5] = (short)f2bf(f01.y);
            b0[6] = (short)f2bf(f01.z); b0[7] = (short)f2bf(f01.w);
            b1[0] = (short)f2bf(f10.x); b1[1] = (short)f2bf(f10.y);
            b1[2] = (short)f2bf(f10.z); b1[3] = (short)f2bf(f10.w);
            b1[4] = (short)f2bf(f11.x); b1[5] = (short)f2bf(f11.y);
            b1[6] = (short)f2bf(f11.z); b1[7] = (short)f2bf(f11.w);
            acc[0][0] = MFMA(a0, b0, acc[0][0]);
            acc[0][1] = MFMA(a0, b1, acc[0][1]);
            acc[1][0] = MFMA(a1, b0, acc[1][0]);
            acc[1][1] = MFMA(a1, b1, acc[1][1]);
        }
#pragma unroll
        for (int f = 0; f < 2; ++f)
#pragma unroll
            for (int g = 0; g < 2; ++g) {
                const int ap = aB + g * 16 + ll;
#pragma unroll
                for (int r = 0; r < 4; ++r) {
                    const int o = oA + f * 16 + lg * 4 + r;
                    W1fT[o * 512 + 256 + ap] = f2bf(acc[f][g][r]);
                }
            }
    }
}

// ===========================================================================
// LDS-staged 128x128-tile GEMM core (unchanged).
// ===========================================================================
#define GEMM_STAGE(AROWP, BROWP)                                              \
    {                                                                         \
        _Pragma("unroll")                                                     \
        for (int i_ = 0; i_ < 4; ++i_) {                                      \
            const int row_ = i_ * 32 + srow;                                  \
            bf16x8 va_ = *(const bf16x8*)(AROWP(row_) + sc8 * 8);             \
            bf16x8 vb_ = *(const bf16x8*)(BROWP(row_) + sc8 * 8);             \
            const int dst_ = (row_ * 8 + (sc8 ^ (row_ & 7))) * 8;             \
            *(bf16x8*)&ldsA[dst_] = va_;                                      \
            *(bf16x8*)&ldsB[dst_] = vb_;                                      \
        }                                                                     \
    }

#define GEMM_FRAGS(k2_)                                                       \
    bf16x8 af[4], bfr[4];                                                     \
    {                                                                         \
        _Pragma("unroll")                                                     \
        for (int fo_ = 0; fo_ < 4; ++fo_) {                                   \
            const int ra_ = wr * 64 + fo_ * 16 + ll;                          \
            af[fo_] = *(const bf16x8*)&ldsA[(ra_ * 8 + (((k2_) * 4 + lg) ^ (ra_ & 7))) * 8]; \
            const int rb_ = wc * 64 + fo_ * 16 + ll;                          \
            bfr[fo_] = *(const bf16x8*)&ldsB[(rb_ * 8 + (((k2_) * 4 + lg) ^ (rb_ & 7))) * 8]; \
        }                                                                     \
    }

#define GEMM_MFMA16()                                                         \
    _Pragma("unroll")                                                         \
    for (int fo_ = 0; fo_ < 4; ++fo_) {                                       \
        _Pragma("unroll")                                                     \
        for (int fn_ = 0; fn_ < 4; ++fn_)                                     \
            acc[fo_][fn_] = MFMA(af[fo_], bfr[fn_], acc[fo_][fn_]);           \
    }

// ---------------------------------------------------------------------------
// QKV projections, LDS-staged. Q -> planar [b][h][n][d].
// K -> frag-packed K'[bh][kb32][j4][lane64][8]  (j = d>>4, lane = hi*32+key&31)
// V -> frag-packed V'[bh][mtile][dc2][mc2][lane64][8] (lane = hi*32 + d&31)
// ---------------------------------------------------------------------------
__global__ __launch_bounds__(256)
void qkv128(const ushortT* __restrict__ xT, const ushortT* __restrict__ srcT,
            const ushortT* __restrict__ WqT, const ushortT* __restrict__ WkT,
            const ushortT* __restrict__ WvT,
            const float* __restrict__ bqs, const float* __restrict__ bks,
            const float* __restrict__ bvs,
            ushortT* __restrict__ QT, ushortT* __restrict__ Kp,
            ushortT* __restrict__ Vp)
{
    __shared__ __align__(16) ushortT ldsA[8192];
    __shared__ __align__(16) ushortT ldsB[8192];
    const int z = blockIdx.z, sel = z >> 1, b = z & 1;
    const int t = threadIdx.x, w = t >> 6, l = t & 63, lg = l >> 4, ll = l & 15;
    const int wr = w >> 1, wc = w & 1;
    const int n0 = blockIdx.x * 128, o0 = blockIdx.y * 128;
    const int srow = t >> 3, sc8 = t & 7;

    const ushortT* Agl;
    const ushortT* Bgl;
    int Arb, Brb;
    if (sel == 0)      { Agl = WqT;  Arb = o0;              Bgl = xT;   Brb = (b << 12) + n0; }
    else if (sel == 1) { Agl = WkT;  Arb = o0;              Bgl = srcT; Brb = (b << 12) + n0; }
    else               { Agl = srcT; Arb = (b << 12) + n0;  Bgl = WvT;  Brb = o0; }

    f32x4 acc[4][4] = {};
#define AROW(r_) (Agl + (size_t)(Arb + (r_)) * 256 + kk)
#define BROW(r_) (Bgl + (size_t)(Brb + (r_)) * 256 + kk)
    for (int kk = 0; kk < 256; kk += 64) {
        GEMM_STAGE(AROW, BROW);
        __syncthreads();
#pragma unroll
        for (int k2 = 0; k2 < 2; ++k2) {
            GEMM_FRAGS(k2);
            GEMM_MFMA16();
        }
        __syncthreads();
    }
#undef AROW
#undef BROW

    if (sel < 2) {
        const float* bias = sel ? bks : bqs;
#pragma unroll
        for (int f = 0; f < 4; ++f) {
            const int ob = o0 + wr * 64 + f * 16 + lg * 4;
            f32x4 bv = *(const f32x4*)&bias[ob];
            const int hh = ob >> 6, d = ob & 63;
#pragma unroll
            for (int g = 0; g < 4; ++g) {
                const int n = n0 + wc * 64 + g * 16 + ll;
                u16x4 pk;
#pragma unroll
                for (int r = 0; r < 4; ++r) pk[r] = f2bf(acc[f][g][r] + bv[r]);
                const int bh = (b << 2) + hh;
                if (sel == 0) {
                    *(u16x4*)&QT[((bh << 12) + n) * 64 + d] = pk;
                } else {
                    // K': ((bh*128 + kb)*4 + j)*512 + (hi*32 + key&31)*8 + e
                    const int kb = n >> 5, ln2 = n & 31;
                    const int j = d >> 4, hi2 = (d >> 3) & 1, e = d & 7;
                    const int addr = (bh << 18) + kb * 2048 + j * 512 + (hi2 * 32 + ln2) * 8 + e;
                    *(u16x4*)&Kp[addr] = pk;
                }
            }
        }
    } else {
#pragma unroll
        for (int g = 0; g < 4; ++g) {
            const int op = o0 + wc * 64 + g * 16 + ll;
            const float bb = bvs[op];
            const int hh = op >> 6, d = op & 63;
            const int bh = (b << 2) + hh;
            const int dc = d >> 5, lnn = d & 31;
#pragma unroll
            for (int f = 0; f < 4; ++f) {
                const int m = n0 + wr * 64 + f * 16 + lg * 4;
                u16x4 pk;
#pragma unroll
                for (int r = 0; r < 4; ++r) pk[r] = f2bf(acc[f][g][r] + bb);
                // V': (((bh*128+mtile)*2+dc)*2+mc)*512 + (hi*32 + d&31)*8 + e
                const int mtile = m >> 5, rm = m & 31;
                const int mc = rm >> 4, hi2 = (rm >> 3) & 1, e = rm & 7;
                const int addr = (bh << 18) + mtile * 2048 + dc * 1024 + mc * 512
                               + (hi2 * 32 + lnn) * 8 + e;
                *(u16x4*)&Vp[addr] = pk;
            }
        }
    }
}

// ---------------------------------------------------------------------------
// h-GEMM (unchanged).
// ---------------------------------------------------------------------------
__global__ __launch_bounds__(256)
void gemmh128(const ushortT* __restrict__ xT, const ushortT* __restrict__ attnT,
              const ushortT* __restrict__ W1fT, const float* __restrict__ bfused,
              ushortT* __restrict__ hT, float* __restrict__ Sp, float* __restrict__ SSp)
{
    __shared__ __align__(16) ushortT ldsA[8192];
    __shared__ __align__(16) ushortT ldsB[8192];
    const int t = threadIdx.x, w = t >> 6, l = t & 63, lg = l >> 4, ll = l & 15;
    const int wr = w >> 1, wc = w & 1;
    const int n0 = blockIdx.x * 128, o0 = blockIdx.y * 128, b = blockIdx.z;
    const int srow = t >> 3, sc8 = t & 7;

    f32x4 acc[4][4] = {};
    for (int kk = 0; kk < 512; kk += 64) {
        const ushortT* Bsrc = (kk < 256) ? xT : attnT;
        const int kb = kk & 255;
#define AROW(r_) (W1fT + (size_t)(o0 + (r_)) * 512 + kk)
#define BROW(r_) (Bsrc + (size_t)((b << 12) + n0 + (r_)) * 256 + kb)
        GEMM_STAGE(AROW, BROW);
#undef AROW
#undef BROW
        __syncthreads();
#pragma unroll
        for (int k2 = 0; k2 < 2; ++k2) {
            GEMM_FRAGS(k2);
            GEMM_MFMA16();
        }
        __syncthreads();
    }

#pragma unroll
    for (int f = 0; f < 4; ++f) {
        const int ob = o0 + wr * 64 + f * 16 + lg * 4;
        f32x4 bv = *(const f32x4*)&bfused[ob];
        f32x4 hv[4];
#pragma unroll
        for (int g = 0; g < 4; ++g) {
            const int n = n0 + wc * 64 + g * 16 + ll;
            u16x4 pk;
#pragma unroll
            for (int r = 0; r < 4; ++r) {
                hv[g][r] = acc[f][g][r] + bv[r];
                pk[r] = f2bf(hv[g][r]);
            }
            *(u16x4*)&hT[(((b << 12) + n) << 9) + ob] = pk;
        }
#pragma unroll
        for (int r = 0; r < 4; ++r) {
            float s  = (hv[0][r] + hv[1][r]) + (hv[2][r] + hv[3][r]);
            float q2 = (hv[0][r] * hv[0][r] + hv[1][r] * hv[1][r]) +
                       (hv[2][r] * hv[2][r] + hv[3][r] * hv[3][r]);
#pragma unroll
            for (int off = 1; off < 16; off <<= 1) {
                s  += __shfl_xor(s, off);
                q2 += __shfl_xor(q2, off);
            }
            if (ll == 0) {
                const int o = ob + r;
                const int pidx = (o * 2 + b) * 64 + blockIdx.x * 2 + wc;
                Sp[pidx] = s;
                SSp[pidx] = q2;
            }
        }
    }
}

// ---------------------------------------------------------------------------
// BN finalize (unchanged).
// ---------------------------------------------------------------------------
__global__ __launch_bounds__(128)
void bn_fin2(const float* __restrict__ S, const float* __restrict__ SS,
             const float* __restrict__ gamma, const float* __restrict__ beta,
             float* __restrict__ scale, float* __restrict__ shift)
{
    const int c = blockIdx.x, t = threadIdx.x;
    float s = S[c * 128 + t];
    float ss = SS[c * 128 + t];
#pragma unroll
    for (int off = 32; off; off >>= 1) {
        s += __shfl_down(s, off);
        ss += __shfl_down(ss, off);
    }
    __shared__ float red[4];
    const int wid = t >> 6;
    if ((t & 63) == 0) { red[wid] = s; red[2 + wid] = ss; }
    __syncthreads();
    if (t == 0) {
        s = red[0] + red[1];
        ss = red[2] + red[3];
        const float cnt = (float)NB * (float)LEN;
        float mean = s / cnt;
        float var = ss / cnt - mean * mean;
        float sc = gamma[c] * rsqrtf(var + EPSBN);
        scale[c] = sc;
        shift[c] = beta[c] - mean * sc;
    }
}

// ---------------------------------------------------------------------------
// Final GEMM (unchanged).
// ---------------------------------------------------------------------------
__global__ __launch_bounds__(256)
void gemmw2_128(const ushortT* __restrict__ hT, const ushortT* __restrict__ W2T,
                const float* __restrict__ bias, const float* __restrict__ scale,
                const float* __restrict__ shift, float* __restrict__ out)
{
    __shared__ __align__(16) ushortT ldsA[8192];
    __shared__ __align__(16) ushortT ldsB[8192];
    const int t = threadIdx.x, w = t >> 6, l = t & 63, lg = l >> 4, ll = l & 15;
    const int wr = w >> 1, wc = w & 1;
    const int n0 = blockIdx.x * 128, o0 = blockIdx.y * 128, b = blockIdx.z;
    const int srow = t >> 3, sc8 = t & 7;

    f32x4 acc[4][4] = {};
    for (int kk = 0; kk < 512; kk += 64) {
#define AROW(r_) (W2T + (size_t)(o0 + (r_)) * 512 + kk)
#define BROW(r_) (hT + (size_t)((b << 12) + n0 + (r_)) * 512 + kk)
        GEMM_STAGE(AROW, BROW);
#undef AROW
#undef BROW
        __syncthreads();
#pragma unroll
        for (int k2 = 0; k2 < 2; ++k2) {
            GEMM_FRAGS(k2);
            const int ch = kk + k2 * 32 + lg * 8;
            f32x4 sc0 = *(const f32x4*)&scale[ch];
            f32x4 sc1 = *(const f32x4*)&scale[ch + 4];
            f32x4 sh0 = *(const f32x4*)&shift[ch];
            f32x4 sh1 = *(const f32x4*)&shift[ch + 4];
#pragma unroll
            for (int fn = 0; fn < 4; ++fn) {
                bf16x8 raw = bfr[fn], bb;
#pragma unroll
                for (int j = 0; j < 4; ++j) {
                    float v0 = fmaxf(bf2f((unsigned short)raw[j]) * sc0[j] + sh0[j], 0.f);
                    float v1 = fmaxf(bf2f((unsigned short)raw[j + 4]) * sc1[j] + sh1[j], 0.f);
                    bb[j] = (short)f2bf(v0);
                    bb[j + 4] = (short)f2bf(v1);
                }
                bfr[fn] = bb;
            }
            GEMM_MFMA16();
        }
        __syncthreads();
    }

#pragma unroll
    for (int f = 0; f < 4; ++f) {
        const int ob = o0 + wr * 64 + f * 16 + lg * 4;
        f32x4 bv = *(const f32x4*)&bias[ob];
#pragma unroll
        for (int g = 0; g < 4; ++g) {
            const int n = n0 + wc * 64 + g * 16 + ll;
#pragma unroll
            for (int r = 0; r < 4; ++r)
                out[(((b << 8) + ob + r) << 12) + n] = acc[f][g][r] + bv[r];
        }
    }
}

// ---------------------------------------------------------------------------
// Flash attention v12: attn9 body with FRAG-PACKED K'/V' loads — every frag
// load is 64 lanes x consecutive 16B = one coalesced 1KB transaction.
// 64q/wave, 4-wave key split, grid 512, native v_exp, phased LDS merge.
// ---------------------------------------------------------------------------
__global__ __launch_bounds__(256)
void attn12(const ushortT* __restrict__ QT, const ushortT* __restrict__ Kp,
            const ushortT* __restrict__ Vp, ushortT* __restrict__ attnT)
{
    __shared__ __align__(16) float olds[6144];
    __shared__ float llds[192];
    const int t = threadIdx.x, w = t >> 6, l = t & 63;
    const int hi = l >> 5, ln = l & 31;
    const int f = blockIdx.x, bh = f & 7, nt = f >> 3;
    const int b = bh >> 2, h = bh & 3;
    const int n0 = nt * 64;

    bf16x8 qf[2][4];
#pragma unroll
    for (int qb = 0; qb < 2; ++qb) {
        const int qrow = ((bh << 12) + n0 + qb * 32 + ln) * 64 + hi * 8;
#pragma unroll
        for (int dblk = 0; dblk < 4; ++dblk)
            qf[qb][dblk] = *(const bf16x8*)&QT[qrow + dblk * 16];
    }

    f32x16 o[2][2] = {};
    float l_loc[2] = {0.f, 0.f};

    // frag-packed bases: wave w owns key-tile kb = s*4 + w
    const ushortT* K2 = Kp + (bh << 18) + (w << 11) + l * 8;   // + s*8192 + j*512
    const ushortT* V2 = Vp + (bh << 18) + (w << 11) + l * 8;   // + s*8192 + frag*512

#pragma unroll 1
    for (int s = 0; s < 32; ++s) {
        const ushortT* Ks = K2 + s * 8192;
        f32x16 st0 = {}, st1 = {};
        {
            bf16x8 ka = *(const bf16x8*)(Ks);
            bf16x8 kb = *(const bf16x8*)(Ks + 512);
            __builtin_amdgcn_s_setprio(1);
            st0 = MFMA32(ka, qf[0][0], st0);
            st1 = MFMA32(ka, qf[1][0], st1);
            st0 = MFMA32(kb, qf[0][1], st0);
            st1 = MFMA32(kb, qf[1][1], st1);
            __builtin_amdgcn_s_setprio(0);
            ka = *(const bf16x8*)(Ks + 1024);
            kb = *(const bf16x8*)(Ks + 1536);
            __builtin_amdgcn_s_setprio(1);
            st0 = MFMA32(ka, qf[0][2], st0);
            st1 = MFMA32(ka, qf[1][2], st1);
            st0 = MFMA32(kb, qf[0][3], st0);
            st1 = MFMA32(kb, qf[1][3], st1);
            __builtin_amdgcn_s_setprio(0);
        }

#pragma unroll
        for (int r = 0; r < 16; ++r) st0[r] = __builtin_amdgcn_exp2f(st0[r]);
#pragma unroll
        for (int r = 0; r < 16; ++r) st1[r] = __builtin_amdgcn_exp2f(st1[r]);
        l_loc[0] += sum16(st0);
        l_loc[1] += sum16(st1);

        bf16x8 pb0[2], pb1[2];
        {
            unsigned int pk0[8], pk1[8];
#pragma unroll
            for (int j = 0; j < 8; ++j) {
                pk0[j] = cvtpk_bf16(st0[2 * j], st0[2 * j + 1]);
                pk1[j] = cvtpk_bf16(st1[2 * j], st1[2 * j + 1]);
            }
#pragma unroll
            for (int sb = 0; sb < 2; ++sb) {
                unsigned int a0 = pk0[4 * sb], b0 = pk0[4 * sb + 2];
                unsigned int a1 = pk0[4 * sb + 1], b1 = pk0[4 * sb + 3];
                asm volatile("v_permlane32_swap_b32 %0, %1" : "+v"(a0), "+v"(b0));
                asm volatile("v_permlane32_swap_b32 %0, %1" : "+v"(a1), "+v"(b1));
                union { unsigned int u[4]; bf16x8 v; } tp;
                tp.u[0] = a0; tp.u[1] = a1; tp.u[2] = b0; tp.u[3] = b1;
                pb0[sb] = tp.v;
                unsigned int c0 = pk1[4 * sb], d0 = pk1[4 * sb + 2];
                unsigned int c1 = pk1[4 * sb + 1], d1 = pk1[4 * sb + 3];
                asm volatile("v_permlane32_swap_b32 %0, %1" : "+v"(c0), "+v"(d0));
                asm volatile("v_permlane32_swap_b32 %0, %1" : "+v"(c1), "+v"(d1));
                union { unsigned int u[4]; bf16x8 v; } tq;
                tq.u[0] = c0; tq.u[1] = c1; tq.u[2] = d0; tq.u[3] = d1;
                pb1[sb] = tq.v;
            }
        }

        const ushortT* Vs = V2 + s * 8192;
        {
            bf16x8 va = *(const bf16x8*)(Vs);            // dc0, mc0
            bf16x8 vb = *(const bf16x8*)(Vs + 512);      // dc0, mc1
            __builtin_amdgcn_s_setprio(1);
            o[0][0] = MFMA32(va, pb0[0], o[0][0]);
            o[1][0] = MFMA32(va, pb1[0], o[1][0]);
            o[0][0] = MFMA32(vb, pb0[1], o[0][0]);
            o[1][0] = MFMA32(vb, pb1[1], o[1][0]);
            __builtin_amdgcn_s_setprio(0);
            va = *(const bf16x8*)(Vs + 1024);            // dc1, mc0
            vb = *(const bf16x8*)(Vs + 1536);            // dc1, mc1
            __builtin_amdgcn_s_setprio(1);
            o[0][1] = MFMA32(va, pb0[0], o[0][1]);
            o[1][1] = MFMA32(va, pb1[0], o[1][1]);
            o[0][1] = MFMA32(vb, pb0[1], o[0][1]);
            o[1][1] = MFMA32(vb, pb1[1], o[1][1]);
            __builtin_amdgcn_s_setprio(0);
        }
    }

    // ---- merge 4 key-split waves (phased per qb, 24KB LDS) ----
    float lw[2];
    lw[0] = l_loc[0] + __shfl_xor(l_loc[0], 32);
    lw[1] = l_loc[1] + __shfl_xor(l_loc[1], 32);
    if (w && hi == 0) {
        llds[(w - 1) * 64 + ln] = lw[0];
        llds[(w - 1) * 64 + 32 + ln] = lw[1];
    }
#pragma unroll
    for (int qb = 0; qb < 2; ++qb) {
        if (w) {
            const int base = (w - 1) * 2048 + l;
#pragma unroll
            for (int r = 0; r < 16; ++r) olds[base + r * 64] = o[qb][0][r];
#pragma unroll
            for (int r = 0; r < 16; ++r) olds[base + (16 + r) * 64] = o[qb][1][r];
        }
        __syncthreads();
        if (w == 0) {
#pragma unroll
            for (int j = 0; j < 3; ++j) {
                const int base = j * 2048 + l;
#pragma unroll
                for (int r = 0; r < 16; ++r) o[qb][0][r] += olds[base + r * 64];
#pragma unroll
                for (int r = 0; r < 16; ++r) o[qb][1][r] += olds[base + (16 + r) * 64];
            }
        }
        __syncthreads();
    }

    if (w == 0) {
        float li[2] = {lw[0], lw[1]};
#pragma unroll
        for (int j = 0; j < 3; ++j) {
            li[0] += llds[j * 64 + ln];
            li[1] += llds[j * 64 + 32 + ln];
        }
#pragma unroll
        for (int qb = 0; qb < 2; ++qb) {
            const float linv = 1.f / li[qb];
            ushortT* orow = attnT + ((((b << 12) + n0 + qb * 32 + ln)) << 8) + (h << 6);
#pragma unroll
            for (int j = 0; j < 8; ++j) {
                const int d0 = ((2 * j) & 3) + 8 * (j >> 1) + 4 * hi;
                *(unsigned int*)&orow[d0] =
                    cvtpk_bf16(o[qb][0][2 * j] * linv, o[qb][0][2 * j + 1] * linv);
                *(unsigned int*)&orow[32 + d0] =
                    cvtpk_bf16(o[qb][1][2 * j] * linv, o[qb][1][2 * j + 1] * linv);
            }
        }
    }
}

extern "C" void kernel_launch(void* const* d_in, const int* in_sizes, int n_in,
                              void* d_out, int out_size, void* d_ws, size_t ws_size,
                              hipStream_t stream)
{
    const float* x   = (const float*)d_in[0];
    const float* src = (const float*)d_in[1];
    const float* Wq  = (const float*)d_in[2];
    const float* bq  = (const float*)d_in[3];
    const float* Wk  = (const float*)d_in[4];
    const float* bk  = (const float*)d_in[5];
    const float* Wv  = (const float*)d_in[6];
    const float* bv  = (const float*)d_in[7];
    const float* Wo  = (const float*)d_in[8];
    const float* bo  = (const float*)d_in[9];
    const float* W1  = (const float*)d_in[10];
    const float* b1  = (const float*)d_in[11];
    const float* gam = (const float*)d_in[12];
    const float* bet = (const float*)d_in[13];
    const float* W2  = (const float*)d_in[14];
    const float* b2  = (const float*)d_in[15];
    float* outp = (float*)d_out;

    char* W = (char*)d_ws;
    ushortT* xT    = (ushortT*)(W);                       // 4MB [2][4096][256]
    ushortT* srcT  = (ushortT*)(W + (4u << 20));          // 4MB
    ushortT* QT    = (ushortT*)(W + (8u << 20));          // 4MB [b][h][n][d]
    ushortT* Kpk   = (ushortT*)(W + (12u << 20));         // 4MB frag-packed K'
    ushortT* Vpk   = (ushortT*)(W + (16u << 20));         // 4MB frag-packed V'
    ushortT* attnT = (ushortT*)(W + (20u << 20));         // 4MB [b][n][256]
    ushortT* hT    = Kpk;                                 // 8MB overlays K'+V' (dead)
    float* Sp  = (float*)(W + (8u << 20));                // 256KB overlays QT (dead)
    float* SSp = (float*)(W + (9u << 20));                // 256KB
    char* WB = W + (24u << 20);
    ushortT* WqT  = (ushortT*)(WB);                       // 128KB
    ushortT* WkT  = (ushortT*)(WB + (128u << 10));
    ushortT* WvT  = (ushortT*)(WB + (256u << 10));
    ushortT* W1fT = (ushortT*)(WB + (640u << 10));        // 512KB [512][512]
    ushortT* W2T  = (ushortT*)(WB + (1152u << 10));       // 256KB [256][512]
    float* bqs    = (float*)(WB + (1408u << 10));
    float* bks    = (float*)(WB + (1409u << 10));
    float* bvs    = (float*)(WB + (1410u << 10));
    float* bfused = (float*)(WB + (1412u << 10));         // 2KB
    float* scl    = (float*)(WB + (1416u << 10));
    float* sft    = (float*)(WB + (1418u << 10));

    prep_all<<<dim3(1024, 9), 256, 0, stream>>>(x, src, Wq, Wk, Wv, Wo, W1, W2,
                                                bq, bk, bv, bo, b1,
                                                WqT, WkT, WvT, W1fT, W2T,
                                                bqs, bks, bvs, bfused, xT, srcT);

    qkv128<<<dim3(32, 2, 6), 256, 0, stream>>>(xT, srcT, WqT, WkT, WvT,
                                               bqs, bks, bvs, QT, Kpk, Vpk);

    attn12<<<dim3(512), dim3(256), 0, stream>>>(QT, Kpk, Vpk, attnT);

    gemmh128<<<dim3(32, 4, 2), 256, 0, stream>>>(xT, attnT, W1fT, bfused, hT, Sp, SSp);

    bn_fin2<<<dim3(512), 128, 0, stream>>>(Sp, SSp, gam, bet, scl, sft);

    gemmw2_128<<<dim3(32, 2, 2), 256, 0, stream>>>(hT, W2T, b2, scl, sft, outp);
}

// Round 14
// 139.100 us; speedup vs baseline: 1.1195x; 1.0406x over previous
//
#include <hip/hip_runtime.h>
#include <hip/hip_bf16.h>
#include <math.h>

#define NB   2
#define DIM  256
#define NH   4
#define DH   64
#define LEN  4096
#define EPSBN 1e-5f
#define QSC  0.18033688f   // 0.125 * log2(e): softmax in exp2 domain

typedef __attribute__((ext_vector_type(8))) short bf16x8;
typedef __attribute__((ext_vector_type(4))) float f32x4;
typedef __attribute__((ext_vector_type(16))) float f32x16;
typedef __attribute__((ext_vector_type(4))) unsigned short u16x4;
typedef unsigned short ushortT;

__device__ __forceinline__ unsigned short f2bf(float f) {
    unsigned int u = __float_as_uint(f);
    u += 0x7FFFu + ((u >> 16) & 1u);
    return (unsigned short)(u >> 16);
}
__device__ __forceinline__ float bf2f(unsigned short u) {
    return __uint_as_float(((unsigned int)u) << 16);
}
__device__ __forceinline__ unsigned int cvtpk_bf16(float lo, float hi) {
    unsigned int r;
    asm volatile("v_cvt_pk_bf16_f32 %0, %1, %2" : "=v"(r) : "v"(lo), "v"(hi));
    return r;
}
__device__ __forceinline__ float sum16(const f32x16& v) {
    float s01 = v[0] + v[1], s23 = v[2] + v[3], s45 = v[4] + v[5], s67 = v[6] + v[7];
    float s89 = v[8] + v[9], sab = v[10] + v[11], scd = v[12] + v[13], sef = v[14] + v[15];
    return ((s01 + s23) + (s45 + s67)) + ((s89 + sab) + (scd + sef));
}
#define MFMA(a, b, c)   __builtin_amdgcn_mfma_f32_16x16x32_bf16((a), (b), (c), 0, 0, 0)
#define MFMA32(a, b, c) __builtin_amdgcn_mfma_f32_32x32x16_bf16((a), (b), (c), 0, 0, 0)

// ---------------------------------------------------------------------------
// Fused prep (unchanged): weight transposes, W1 x-half, W2T, biases,
// activation packT, Wo*W1m weight-fusion (y=8).
// ---------------------------------------------------------------------------
__global__ __launch_bounds__(256)
void prep_all(const float* __restrict__ x, const float* __restrict__ src,
              const float* __restrict__ Wq, const float* __restrict__ Wk,
              const float* __restrict__ Wv, const float* __restrict__ Wo,
              const float* __restrict__ W1, const float* __restrict__ W2,
              const float* __restrict__ bq, const float* __restrict__ bk,
              const float* __restrict__ bv, const float* __restrict__ bo,
              const float* __restrict__ b1v,
              ushortT* WqT, ushortT* WkT, ushortT* WvT,
              ushortT* W1fT, ushortT* W2T,
              float* bqs, float* bks, float* bvs, float* bfused,
              ushortT* __restrict__ xT, ushortT* __restrict__ srcT)
{
    const int y = blockIdx.y;
    const int idx = blockIdx.x * 256 + threadIdx.x;
    const int t = threadIdx.x;
    if (y <= 2) {
        if (idx < 65536) {
            int op = idx >> 8, i = idx & 255;
            int o = (op & 63) * 4 + (op >> 6);
            if (y == 0)      WqT[idx] = f2bf(Wq[i * 256 + o] * QSC);
            else if (y == 1) WkT[idx] = f2bf(Wk[i * 256 + o]);
            else             WvT[idx] = f2bf(Wv[i * 256 + o]);
        }
    } else if (y == 3) {
        int o = idx >> 9, i = idx & 511;
        if (i < 256) W1fT[o * 512 + i] = f2bf(W1[i * 512 + o]);
    } else if (y == 4) {
        if (idx < 131072) { int o = idx >> 9, i = idx & 511; W2T[idx] = f2bf(W2[i * 256 + o]); }
    } else if (y == 5) {
        if (blockIdx.x == 0 && idx < 256) {
            int o = (idx & 63) * 4 + (idx >> 6);
            bqs[idx] = bq[o] * QSC;
            bks[idx] = bk[o];
            bvs[idx] = bv[o];
        }
    } else if (y <= 7) {
        const int bid = blockIdx.x + (y - 6) * 1024;
        const int c0 = (bid & 31) * 8;
        const int n0 = ((bid >> 5) & 15) * 256;
        const int z = bid >> 9;
        const int b = z & 1;
        const float* in = (z >> 1) ? src : x;
        ushortT* out = (z >> 1) ? srcT : xT;
        const int n = n0 + t;
        bf16x8 v;
#pragma unroll
        for (int j = 0; j < 8; ++j)
            v[j] = (short)f2bf(in[(((b << 8) + c0 + j) << 12) + n]);
        *(bf16x8*)&out[(((b << 12) + n) << 8) + c0] = v;
    } else {
        if (blockIdx.x >= 40) return;
        const int oy = blockIdx.x / 5, xi = blockIdx.x % 5;
        __shared__ float red[4][64];
        if (xi == 4) {
            const int part = t >> 6, oo = t & 63;
            const int o = oy * 64 + oo;
            float s = 0.f;
            for (int c = part * 64; c < part * 64 + 64; ++c)
                s += bo[c] * W1[(256 + c) * 512 + o];
            red[part][oo] = s;
            __syncthreads();
            if (part == 0)
                bfused[o] = ((red[0][oo] + red[1][oo]) + (red[2][oo] + red[3][oo])) + b1v[o];
            return;
        }
        const int w = t >> 6, l2 = t & 63, lg = l2 >> 4, ll = l2 & 15;
        const int wr = w >> 1, wc = w & 1;
        const int a0t = xi * 64, o0 = oy * 64;
        const int oA = o0 + wr * 32;
        const int aB = a0t + wc * 32;
        f32x4 acc[2][2] = {};
        const int ra = aB + ll, rb = aB + 16 + ll;
        const int r0 = (ra & 63) * 4 + (ra >> 6);
        const int r1 = (rb & 63) * 4 + (rb >> 6);
#pragma unroll
        for (int kk = 0; kk < 256; kk += 32) {
            const int cbase = 256 + kk + lg * 8;
            bf16x8 a0, a1;
#pragma unroll
            for (int j = 0; j < 8; ++j) {
                a0[j] = (short)f2bf(W1[(size_t)(cbase + j) * 512 + oA + ll]);
                a1[j] = (short)f2bf(W1[(size_t)(cbase + j) * 512 + oA + 16 + ll]);
            }
            const float* p0 = Wo + r0 * 256 + kk + lg * 8;
            const float* p1 = Wo + r1 * 256 + kk + lg * 8;
            float4 f00 = *(const float4*)p0, f01 = *(const float4*)(p0 + 4);
            float4 f10 = *(const float4*)p1, f11 = *(const float4*)(p1 + 4);
            bf16x8 b0, b1;
            b0[0] = (short)f2bf(f00.x); b0[1] = (short)f2bf(f00.y);
            b0[2] = (short)f2bf(f00.z); b0[3] = (short)f2bf(f00.w);
            b0[4] = (short)f2bf(f01.x); b0[5] = (short)f2bf(f01.y);
            b0[6] = (short)f2bf(f01.z); b0[7] = (short)f2bf(f01.w);
            b1[0] = (short)f2bf(f10.x); b1[1] = (short)f2bf(f10.y);
            b1[2] = (short)f2bf(f10.z); b1[3] = (short)f2bf(f10.w);
            b1[4] = (short)f2bf(f11.x); b1[5] = (short)f2bf(f11.y);
            b1[6] = (short)f2bf(f11.z); b1[7] = (short)f2bf(f11.w);
            acc[0][0] = MFMA(a0, b0, acc[0][0]);
            acc[0][1] = MFMA(a0, b1, acc[0][1]);
            acc[1][0] = MFMA(a1, b0, acc[1][0]);
            acc[1][1] = MFMA(a1, b1, acc[1][1]);
        }
#pragma unroll
        for (int f = 0; f < 2; ++f)
#pragma unroll
            for (int g = 0; g < 2; ++g) {
                const int ap = aB + g * 16 + ll;
#pragma unroll
                for (int r = 0; r < 4; ++r) {
                    const int o = oA + f * 16 + lg * 4 + r;
                    W1fT[o * 512 + 256 + ap] = f2bf(acc[f][g][r]);
                }
            }
    }
}

// ===========================================================================
// LDS-staged 128x128-tile GEMM core (unchanged).
// ===========================================================================
#define GEMM_STAGE(AROWP, BROWP)                                              \
    {                                                                         \
        _Pragma("unroll")                                                     \
        for (int i_ = 0; i_ < 4; ++i_) {                                      \
            const int row_ = i_ * 32 + srow;                                  \
            bf16x8 va_ = *(const bf16x8*)(AROWP(row_) + sc8 * 8);             \
            bf16x8 vb_ = *(const bf16x8*)(BROWP(row_) + sc8 * 8);             \
            const int dst_ = (row_ * 8 + (sc8 ^ (row_ & 7))) * 8;             \
            *(bf16x8*)&ldsA[dst_] = va_;                                      \
            *(bf16x8*)&ldsB[dst_] = vb_;                                      \
        }                                                                     \
    }

#define GEMM_FRAGS(k2_)                                                       \
    bf16x8 af[4], bfr[4];                                                     \
    {                                                                         \
        _Pragma("unroll")                                                     \
        for (int fo_ = 0; fo_ < 4; ++fo_) {                                   \
            const int ra_ = wr * 64 + fo_ * 16 + ll;                          \
            af[fo_] = *(const bf16x8*)&ldsA[(ra_ * 8 + (((k2_) * 4 + lg) ^ (ra_ & 7))) * 8]; \
            const int rb_ = wc * 64 + fo_ * 16 + ll;                          \
            bfr[fo_] = *(const bf16x8*)&ldsB[(rb_ * 8 + (((k2_) * 4 + lg) ^ (rb_ & 7))) * 8]; \
        }                                                                     \
    }

#define GEMM_MFMA16()                                                         \
    _Pragma("unroll")                                                         \
    for (int fo_ = 0; fo_ < 4; ++fo_) {                                       \
        _Pragma("unroll")                                                     \
        for (int fn_ = 0; fn_ < 4; ++fn_)                                     \
            acc[fo_][fn_] = MFMA(af[fo_], bfr[fn_], acc[fo_][fn_]);           \
    }

// ---------------------------------------------------------------------------
// QKV projections, LDS-staged (unchanged from round 13).
// ---------------------------------------------------------------------------
__global__ __launch_bounds__(256)
void qkv128(const ushortT* __restrict__ xT, const ushortT* __restrict__ srcT,
            const ushortT* __restrict__ WqT, const ushortT* __restrict__ WkT,
            const ushortT* __restrict__ WvT,
            const float* __restrict__ bqs, const float* __restrict__ bks,
            const float* __restrict__ bvs,
            ushortT* __restrict__ QT, ushortT* __restrict__ Kp,
            ushortT* __restrict__ Vp)
{
    __shared__ __align__(16) ushortT ldsA[8192];
    __shared__ __align__(16) ushortT ldsB[8192];
    const int z = blockIdx.z, sel = z >> 1, b = z & 1;
    const int t = threadIdx.x, w = t >> 6, l = t & 63, lg = l >> 4, ll = l & 15;
    const int wr = w >> 1, wc = w & 1;
    const int n0 = blockIdx.x * 128, o0 = blockIdx.y * 128;
    const int srow = t >> 3, sc8 = t & 7;

    const ushortT* Agl;
    const ushortT* Bgl;
    int Arb, Brb;
    if (sel == 0)      { Agl = WqT;  Arb = o0;              Bgl = xT;   Brb = (b << 12) + n0; }
    else if (sel == 1) { Agl = WkT;  Arb = o0;              Bgl = srcT; Brb = (b << 12) + n0; }
    else               { Agl = srcT; Arb = (b << 12) + n0;  Bgl = WvT;  Brb = o0; }

    f32x4 acc[4][4] = {};
#define AROW(r_) (Agl + (size_t)(Arb + (r_)) * 256 + kk)
#define BROW(r_) (Bgl + (size_t)(Brb + (r_)) * 256 + kk)
    for (int kk = 0; kk < 256; kk += 64) {
        GEMM_STAGE(AROW, BROW);
        __syncthreads();
#pragma unroll
        for (int k2 = 0; k2 < 2; ++k2) {
            GEMM_FRAGS(k2);
            GEMM_MFMA16();
        }
        __syncthreads();
    }
#undef AROW
#undef BROW

    if (sel < 2) {
        const float* bias = sel ? bks : bqs;
#pragma unroll
        for (int f = 0; f < 4; ++f) {
            const int ob = o0 + wr * 64 + f * 16 + lg * 4;
            f32x4 bv = *(const f32x4*)&bias[ob];
            const int hh = ob >> 6, d = ob & 63;
#pragma unroll
            for (int g = 0; g < 4; ++g) {
                const int n = n0 + wc * 64 + g * 16 + ll;
                u16x4 pk;
#pragma unroll
                for (int r = 0; r < 4; ++r) pk[r] = f2bf(acc[f][g][r] + bv[r]);
                const int bh = (b << 2) + hh;
                if (sel == 0) {
                    *(u16x4*)&QT[((bh << 12) + n) * 64 + d] = pk;
                } else {
                    const int kb = n >> 5, ln2 = n & 31;
                    const int j = d >> 4, hi2 = (d >> 3) & 1, e = d & 7;
                    const int addr = (bh << 18) + kb * 2048 + j * 512 + (hi2 * 32 + ln2) * 8 + e;
                    *(u16x4*)&Kp[addr] = pk;
                }
            }
        }
    } else {
#pragma unroll
        for (int g = 0; g < 4; ++g) {
            const int op = o0 + wc * 64 + g * 16 + ll;
            const float bb = bvs[op];
            const int hh = op >> 6, d = op & 63;
            const int bh = (b << 2) + hh;
            const int dc = d >> 5, lnn = d & 31;
#pragma unroll
            for (int f = 0; f < 4; ++f) {
                const int m = n0 + wr * 64 + f * 16 + lg * 4;
                u16x4 pk;
#pragma unroll
                for (int r = 0; r < 4; ++r) pk[r] = f2bf(acc[f][g][r] + bb);
                const int mtile = m >> 5, rm = m & 31;
                const int mc = rm >> 4, hi2 = (rm >> 3) & 1, e = rm & 7;
                const int addr = (bh << 18) + mtile * 2048 + dc * 1024 + mc * 512
                               + (hi2 * 32 + lnn) * 8 + e;
                *(u16x4*)&Vp[addr] = pk;
            }
        }
    }
}

// ---------------------------------------------------------------------------
// h-GEMM (unchanged).
// ---------------------------------------------------------------------------
__global__ __launch_bounds__(256)
void gemmh128(const ushortT* __restrict__ xT, const ushortT* __restrict__ attnT,
              const ushortT* __restrict__ W1fT, const float* __restrict__ bfused,
              ushortT* __restrict__ hT, float* __restrict__ Sp, float* __restrict__ SSp)
{
    __shared__ __align__(16) ushortT ldsA[8192];
    __shared__ __align__(16) ushortT ldsB[8192];
    const int t = threadIdx.x, w = t >> 6, l = t & 63, lg = l >> 4, ll = l & 15;
    const int wr = w >> 1, wc = w & 1;
    const int n0 = blockIdx.x * 128, o0 = blockIdx.y * 128, b = blockIdx.z;
    const int srow = t >> 3, sc8 = t & 7;

    f32x4 acc[4][4] = {};
    for (int kk = 0; kk < 512; kk += 64) {
        const ushortT* Bsrc = (kk < 256) ? xT : attnT;
        const int kb = kk & 255;
#define AROW(r_) (W1fT + (size_t)(o0 + (r_)) * 512 + kk)
#define BROW(r_) (Bsrc + (size_t)((b << 12) + n0 + (r_)) * 256 + kb)
        GEMM_STAGE(AROW, BROW);
#undef AROW
#undef BROW
        __syncthreads();
#pragma unroll
        for (int k2 = 0; k2 < 2; ++k2) {
            GEMM_FRAGS(k2);
            GEMM_MFMA16();
        }
        __syncthreads();
    }

#pragma unroll
    for (int f = 0; f < 4; ++f) {
        const int ob = o0 + wr * 64 + f * 16 + lg * 4;
        f32x4 bv = *(const f32x4*)&bfused[ob];
        f32x4 hv[4];
#pragma unroll
        for (int g = 0; g < 4; ++g) {
            const int n = n0 + wc * 64 + g * 16 + ll;
            u16x4 pk;
#pragma unroll
            for (int r = 0; r < 4; ++r) {
                hv[g][r] = acc[f][g][r] + bv[r];
                pk[r] = f2bf(hv[g][r]);
            }
            *(u16x4*)&hT[(((b << 12) + n) << 9) + ob] = pk;
        }
#pragma unroll
        for (int r = 0; r < 4; ++r) {
            float s  = (hv[0][r] + hv[1][r]) + (hv[2][r] + hv[3][r]);
            float q2 = (hv[0][r] * hv[0][r] + hv[1][r] * hv[1][r]) +
                       (hv[2][r] * hv[2][r] + hv[3][r] * hv[3][r]);
#pragma unroll
            for (int off = 1; off < 16; off <<= 1) {
                s  += __shfl_xor(s, off);
                q2 += __shfl_xor(q2, off);
            }
            if (ll == 0) {
                const int o = ob + r;
                const int pidx = (o * 2 + b) * 64 + blockIdx.x * 2 + wc;
                Sp[pidx] = s;
                SSp[pidx] = q2;
            }
        }
    }
}

// ---------------------------------------------------------------------------
// BN finalize (unchanged).
// ---------------------------------------------------------------------------
__global__ __launch_bounds__(128)
void bn_fin2(const float* __restrict__ S, const float* __restrict__ SS,
             const float* __restrict__ gamma, const float* __restrict__ beta,
             float* __restrict__ scale, float* __restrict__ shift)
{
    const int c = blockIdx.x, t = threadIdx.x;
    float s = S[c * 128 + t];
    float ss = SS[c * 128 + t];
#pragma unroll
    for (int off = 32; off; off >>= 1) {
        s += __shfl_down(s, off);
        ss += __shfl_down(ss, off);
    }
    __shared__ float red[4];
    const int wid = t >> 6;
    if ((t & 63) == 0) { red[wid] = s; red[2 + wid] = ss; }
    __syncthreads();
    if (t == 0) {
        s = red[0] + red[1];
        ss = red[2] + red[3];
        const float cnt = (float)NB * (float)LEN;
        float mean = s / cnt;
        float var = ss / cnt - mean * mean;
        float sc = gamma[c] * rsqrtf(var + EPSBN);
        scale[c] = sc;
        shift[c] = beta[c] - mean * sc;
    }
}

// ---------------------------------------------------------------------------
// Final GEMM (unchanged).
// ---------------------------------------------------------------------------
__global__ __launch_bounds__(256)
void gemmw2_128(const ushortT* __restrict__ hT, const ushortT* __restrict__ W2T,
                const float* __restrict__ bias, const float* __restrict__ scale,
                const float* __restrict__ shift, float* __restrict__ out)
{
    __shared__ __align__(16) ushortT ldsA[8192];
    __shared__ __align__(16) ushortT ldsB[8192];
    const int t = threadIdx.x, w = t >> 6, l = t & 63, lg = l >> 4, ll = l & 15;
    const int wr = w >> 1, wc = w & 1;
    const int n0 = blockIdx.x * 128, o0 = blockIdx.y * 128, b = blockIdx.z;
    const int srow = t >> 3, sc8 = t & 7;

    f32x4 acc[4][4] = {};
    for (int kk = 0; kk < 512; kk += 64) {
#define AROW(r_) (W2T + (size_t)(o0 + (r_)) * 512 + kk)
#define BROW(r_) (hT + (size_t)((b << 12) + n0 + (r_)) * 512 + kk)
        GEMM_STAGE(AROW, BROW);
#undef AROW
#undef BROW
        __syncthreads();
#pragma unroll
        for (int k2 = 0; k2 < 2; ++k2) {
            GEMM_FRAGS(k2);
            const int ch = kk + k2 * 32 + lg * 8;
            f32x4 sc0 = *(const f32x4*)&scale[ch];
            f32x4 sc1 = *(const f32x4*)&scale[ch + 4];
            f32x4 sh0 = *(const f32x4*)&shift[ch];
            f32x4 sh1 = *(const f32x4*)&shift[ch + 4];
#pragma unroll
            for (int fn = 0; fn < 4; ++fn) {
                bf16x8 raw = bfr[fn], bb;
#pragma unroll
                for (int j = 0; j < 4; ++j) {
                    float v0 = fmaxf(bf2f((unsigned short)raw[j]) * sc0[j] + sh0[j], 0.f);
                    float v1 = fmaxf(bf2f((unsigned short)raw[j + 4]) * sc1[j] + sh1[j], 0.f);
                    bb[j] = (short)f2bf(v0);
                    bb[j + 4] = (short)f2bf(v1);
                }
                bfr[fn] = bb;
            }
            GEMM_MFMA16();
        }
        __syncthreads();
    }

#pragma unroll
    for (int f = 0; f < 4; ++f) {
        const int ob = o0 + wr * 64 + f * 16 + lg * 4;
        f32x4 bv = *(const f32x4*)&bias[ob];
#pragma unroll
        for (int g = 0; g < 4; ++g) {
            const int n = n0 + wc * 64 + g * 16 + ll;
#pragma unroll
            for (int r = 0; r < 4; ++r)
                out[(((b << 8) + ob + r) << 12) + n] = acc[f][g][r] + bv[r];
        }
    }
}

// ---------------------------------------------------------------------------
// Flash attention v13: 32q/wave to fit the 128-reg occupancy bucket
// (4 waves/SIMD). Frag-packed K'/V' coalesced loads (round-13 win kept).
// 4-wave key split, grid 1024 (4 blocks/CU), single-phase merge (24KB LDS).
// ---------------------------------------------------------------------------
__global__ __launch_bounds__(256)
void attn13(const ushortT* __restrict__ QT, const ushortT* __restrict__ Kp,
            const ushortT* __restrict__ Vp, ushortT* __restrict__ attnT)
{
    __shared__ __align__(16) float olds[6144];   // 3 regions x 2048 f32
    __shared__ float llds[96];
    const int t = threadIdx.x, w = t >> 6, l = t & 63;
    const int hi = l >> 5, ln = l & 31;
    const int f = blockIdx.x, bh = f & 7, nt = f >> 3;   // nt 0..127
    const int b = bh >> 2, h = bh & 3;
    const int n0 = nt * 32;

    // Q B-frags for this wave's 32 q (col = q = ln, k = d), QSC pre-folded
    bf16x8 qf[4];
    {
        const int qrow = ((bh << 12) + n0 + ln) * 64 + hi * 8;
#pragma unroll
        for (int dblk = 0; dblk < 4; ++dblk)
            qf[dblk] = *(const bf16x8*)&QT[qrow + dblk * 16];
    }

    f32x16 o0 = {}, o1 = {};
    float l_loc = 0.f;

    // frag-packed bases: wave w owns key-tile kb = s*4 + w
    const ushortT* K2 = Kp + (bh << 18) + (w << 11) + l * 8;
    const ushortT* V2 = Vp + (bh << 18) + (w << 11) + l * 8;

#pragma unroll 1
    for (int s = 0; s < 32; ++s) {
        const ushortT* Ks = K2 + s * 8192;
        f32x16 st = {};
        {
            bf16x8 ka = *(const bf16x8*)(Ks);
            bf16x8 kb = *(const bf16x8*)(Ks + 512);
            __builtin_amdgcn_s_setprio(1);
            st = MFMA32(ka, qf[0], st);
            st = MFMA32(kb, qf[1], st);
            __builtin_amdgcn_s_setprio(0);
            ka = *(const bf16x8*)(Ks + 1024);
            kb = *(const bf16x8*)(Ks + 1536);
            __builtin_amdgcn_s_setprio(1);
            st = MFMA32(ka, qf[2], st);
            st = MFMA32(kb, qf[3], st);
            __builtin_amdgcn_s_setprio(0);
        }

        // ---- p = exp2(st), single v_exp each (scores bounded) ----
#pragma unroll
        for (int r = 0; r < 16; ++r) st[r] = __builtin_amdgcn_exp2f(st[r]);
        l_loc += sum16(st);

        // ---- P -> bf16 PV B-frags: cvt_pk + permlane32_swap ----
        bf16x8 pb[2];
        {
            unsigned int pk0[8];
#pragma unroll
            for (int j = 0; j < 8; ++j)
                pk0[j] = cvtpk_bf16(st[2 * j], st[2 * j + 1]);
#pragma unroll
            for (int sb = 0; sb < 2; ++sb) {
                unsigned int a0 = pk0[4 * sb], b0 = pk0[4 * sb + 2];
                unsigned int a1 = pk0[4 * sb + 1], b1 = pk0[4 * sb + 3];
                asm volatile("v_permlane32_swap_b32 %0, %1" : "+v"(a0), "+v"(b0));
                asm volatile("v_permlane32_swap_b32 %0, %1" : "+v"(a1), "+v"(b1));
                union { unsigned int u[4]; bf16x8 v; } tp;
                tp.u[0] = a0; tp.u[1] = a1; tp.u[2] = b0; tp.u[3] = b1;
                pb[sb] = tp.v;
            }
        }

        const ushortT* Vs = V2 + s * 8192;
        {
            bf16x8 va = *(const bf16x8*)(Vs);            // dc0, mc0
            bf16x8 vb = *(const bf16x8*)(Vs + 512);      // dc0, mc1
            __builtin_amdgcn_s_setprio(1);
            o0 = MFMA32(va, pb[0], o0);
            o0 = MFMA32(vb, pb[1], o0);
            __builtin_amdgcn_s_setprio(0);
            va = *(const bf16x8*)(Vs + 1024);            // dc1, mc0
            vb = *(const bf16x8*)(Vs + 1536);            // dc1, mc1
            __builtin_amdgcn_s_setprio(1);
            o1 = MFMA32(va, pb[0], o1);
            o1 = MFMA32(vb, pb[1], o1);
            __builtin_amdgcn_s_setprio(0);
        }
    }

    // ---- merge 4 key-split waves (single phase, 24 KB LDS) ----
    float lw = l_loc + __shfl_xor(l_loc, 32);
    if (w && hi == 0) llds[(w - 1) * 32 + ln] = lw;
    if (w) {
        const int base = (w - 1) * 2048 + l;
#pragma unroll
        for (int r = 0; r < 16; ++r) olds[base + r * 64] = o0[r];
#pragma unroll
        for (int r = 0; r < 16; ++r) olds[base + (16 + r) * 64] = o1[r];
    }
    __syncthreads();
    if (w == 0) {
        float li = lw;
#pragma unroll
        for (int j = 0; j < 3; ++j) {
            li += llds[j * 32 + ln];
            const int base = j * 2048 + l;
#pragma unroll
            for (int r = 0; r < 16; ++r) o0[r] += olds[base + r * 64];
#pragma unroll
            for (int r = 0; r < 16; ++r) o1[r] += olds[base + (16 + r) * 64];
        }
        const float linv = 1.f / li;
        ushortT* orow = attnT + ((((b << 12) + n0 + ln)) << 8) + (h << 6);
#pragma unroll
        for (int j = 0; j < 8; ++j) {
            const int d0 = ((2 * j) & 3) + 8 * (j >> 1) + 4 * hi;
            *(unsigned int*)&orow[d0] =
                cvtpk_bf16(o0[2 * j] * linv, o0[2 * j + 1] * linv);
            *(unsigned int*)&orow[32 + d0] =
                cvtpk_bf16(o1[2 * j] * linv, o1[2 * j + 1] * linv);
        }
    }
}

extern "C" void kernel_launch(void* const* d_in, const int* in_sizes, int n_in,
                              void* d_out, int out_size, void* d_ws, size_t ws_size,
                              hipStream_t stream)
{
    const float* x   = (const float*)d_in[0];
    const float* src = (const float*)d_in[1];
    const float* Wq  = (const float*)d_in[2];
    const float* bq  = (const float*)d_in[3];
    const float* Wk  = (const float*)d_in[4];
    const float* bk  = (const float*)d_in[5];
    const float* Wv  = (const float*)d_in[6];
    const float* bv  = (const float*)d_in[7];
    const float* Wo  = (const float*)d_in[8];
    const float* bo  = (const float*)d_in[9];
    const float* W1  = (const float*)d_in[10];
    const float* b1  = (const float*)d_in[11];
    const float* gam = (const float*)d_in[12];
    const float* bet = (const float*)d_in[13];
    const float* W2  = (const float*)d_in[14];
    const float* b2  = (const float*)d_in[15];
    float* outp = (float*)d_out;

    char* W = (char*)d_ws;
    ushortT* xT    = (ushortT*)(W);                       // 4MB [2][4096][256]
    ushortT* srcT  = (ushortT*)(W + (4u << 20));          // 4MB
    ushortT* QT    = (ushortT*)(W + (8u << 20));          // 4MB [b][h][n][d]
    ushortT* Kpk   = (ushortT*)(W + (12u << 20));         // 4MB frag-packed K'
    ushortT* Vpk   = (ushortT*)(W + (16u << 20));         // 4MB frag-packed V'
    ushortT* attnT = (ushortT*)(W + (20u << 20));         // 4MB [b][n][256]
    ushortT* hT    = Kpk;                                 // 8MB overlays K'+V' (dead)
    float* Sp  = (float*)(W + (8u << 20));                // 256KB overlays QT (dead)
    float* SSp = (float*)(W + (9u << 20));                // 256KB
    char* WB = W + (24u << 20);
    ushortT* WqT  = (ushortT*)(WB);                       // 128KB
    ushortT* WkT  = (ushortT*)(WB + (128u << 10));
    ushortT* WvT  = (ushortT*)(WB + (256u << 10));
    ushortT* W1fT = (ushortT*)(WB + (640u << 10));        // 512KB [512][512]
    ushortT* W2T  = (ushortT*)(WB + (1152u << 10));       // 256KB [256][512]
    float* bqs    = (float*)(WB + (1408u << 10));
    float* bks    = (float*)(WB + (1409u << 10));
    float* bvs    = (float*)(WB + (1410u << 10));
    float* bfused = (float*)(WB + (1412u << 10));         // 2KB
    float* scl    = (float*)(WB + (1416u << 10));
    float* sft    = (float*)(WB + (1418u << 10));

    prep_all<<<dim3(1024, 9), 256, 0, stream>>>(x, src, Wq, Wk, Wv, Wo, W1, W2,
                                                bq, bk, bv, bo, b1,
                                                WqT, WkT, WvT, W1fT, W2T,
                                                bqs, bks, bvs, bfused, xT, srcT);

    qkv128<<<dim3(32, 2, 6), 256, 0, stream>>>(xT, srcT, WqT, WkT, WvT,
                                               bqs, bks, bvs, QT, Kpk, Vpk);

    attn13<<<dim3(1024), dim3(256), 0, stream>>>(QT, Kpk, Vpk, attnT);

    gemmh128<<<dim3(32, 4, 2), 256, 0, stream>>>(xT, attnT, W1fT, bfused, hT, Sp, SSp);

    bn_fin2<<<dim3(512), 128, 0, stream>>>(Sp, SSp, gam, bet, scl, sft);

    gemmw2_128<<<dim3(32, 2, 2), 256, 0, stream>>>(hT, W2T, b2, scl, sft, outp);
}